// Round 8
// baseline (81.857 us; speedup 1.0000x reference)
//
#include <hip/hip_runtime.h>
#include <hip/hip_bf16.h>
#include <stdint.h>

// Problem constants (B=64, L=512, H=32, D=128, 21 amino acids)
#define NH  32
#define NL  512
#define ND  128
#define NB  64
#define NAA 21

// ws layout:
//   Ewsw: bf16 exp(scores) UNNORMALIZED, swizzled 8KB tiles [h][it64][kc]  16 MB @ 0
//   Qb/Kb: bf16 swizzled 8KB tiles [h][pt 0..7][dc 0..1] (64 pos x 64 d)   2 MB each
//   Zg  : f32 row sums [h][i]                                              64 KB
#define EW_OFF 0
#define QB_OFF (16u << 20)
#define KB_OFF (18u << 20)
#define ZG_OFF (20u << 20)

typedef short bf16x8 __attribute__((ext_vector_type(8)));
typedef float f32x4  __attribute__((ext_vector_type(4)));

static __device__ __forceinline__ uint32_t bf16rtn(float f) {
    uint32_t u = __float_as_uint(f);
    return (u + 0x7fffu + ((u >> 16) & 1u)) >> 16;
}
static __device__ __forceinline__ void gl16(const void* g, void* l) {
    __builtin_amdgcn_global_load_lds(
        (const __attribute__((address_space(1))) uint32_t*)g,
        (__attribute__((address_space(3))) uint32_t*)l, 16, 0, 0);
}
// swizzled byte within a 64x64 bf16 tile: (r*128 + kk*2) ^ ((r&7)<<4)

// ---------------------------------------------------------------------------
// Q,K f32 -> bf16 swizzled tiles.  2^21 threads: bit20 selects Q/K.
__global__ void prep_qk(const float* __restrict__ Q, const float* __restrict__ K,
                        uint32_t* __restrict__ Qb, uint32_t* __restrict__ Kb) {
    uint32_t tid = blockIdx.x * 256 + threadIdx.x;
    const float* src = (tid >> 20) ? K : Q;
    uint32_t*    dst = (tid >> 20) ? Kb : Qb;
    uint32_t p = tid & 0xFFFFFu;
    uint32_t kk2 = p & 31, r = (p >> 5) & 63, dc = (p >> 11) & 1;
    uint32_t pt = (p >> 12) & 7, h = p >> 15;
    uint32_t pos = pt * 64 + r, d0 = dc * 64 + kk2 * 2;
    float2 v = *(const float2*)(src + ((size_t)(h * NL + pos) * ND + d0));
    uint32_t val = bf16rtn(v.x) | (bf16rtn(v.y) << 16);
    uint32_t byte = (r * 128 + kk2 * 4) ^ ((r & 7) << 4);
    dst[((((h * 8 + pt) * 2 + dc)) << 11) + (byte >> 2)] = val;
}

// ---------------------------------------------------------------------------
// scores via MFMA, SWAPPED operands: S^T = K(j rows) x Q(i cols) over d=128.
#define SC_QS 0        // 16KB: Q tiles dc=0,1
#define SC_KS 16384    // 32KB: K subchunk tiles q = jt*2+dc
#define SC_ZS 49152    // 64 f32
#define SC_TOT 49408

__global__ __launch_bounds__(512)
void scores_mfma(const uint8_t* __restrict__ Qb, const uint8_t* __restrict__ Kb,
                 uint8_t* __restrict__ Ewsw, float* __restrict__ Zg) {
    extern __shared__ uint8_t smem[];
    int h = blockIdx.x >> 3, it = blockIdx.x & 7;
    int t = threadIdx.x, lane = t & 63, wv = t >> 6;
    int wm = wv >> 1, wn = wv & 1;   // 4(Mj) x 2(Ni)

    const uint8_t* qsrc = Qb + (((size_t)(h * 8 + it) * 2) << 13);
    gl16(qsrc + t * 16,        smem + SC_QS + t * 16);
    gl16(qsrc + 8192 + t * 16, smem + SC_QS + 8192 + t * 16);
    if (t < 64) *(float*)(smem + SC_ZS + t * 4) = 0.f;

    float zp[2] = {0.f, 0.f};
    for (int sc = 0; sc < 4; ++sc) {
        __syncthreads();   // prev compute done reading Ks (and 1st: covers Q/Zs)
        const uint8_t* ksrc = Kb + (((size_t)(h * 8 + sc * 2) * 2) << 13);
#pragma unroll
        for (int q = 0; q < 4; ++q)
            gl16(ksrc + q * 8192 + t * 16, smem + SC_KS + q * 8192 + t * 16);
        __syncthreads();   // implicit vmcnt(0): K staged

        f32x4 acc[2][2];
#pragma unroll
        for (int fm = 0; fm < 2; ++fm)
#pragma unroll
            for (int fn = 0; fn < 2; ++fn) acc[fm][fn] = (f32x4){0.f,0.f,0.f,0.f};

#pragma unroll
        for (int ks = 0; ks < 4; ++ks) {
            int kb = ((ks & 1) * 32 + (lane >> 4) * 8) * 2;
            int dc = ks >> 1;
            bf16x8 af[2], bfr[2];
#pragma unroll
            for (int fm = 0; fm < 2; ++fm) {
                int rr = wm * 32 + fm * 16 + (lane & 15);     // j in [0,128)
                int rt = rr >> 6, r6 = rr & 63;
                af[fm] = *(bf16x8*)(smem + SC_KS + (rt * 2 + dc) * 8192 +
                          (((uint32_t)(r6 * 128 + kb)) ^ ((r6 & 7) << 4)));
            }
#pragma unroll
            for (int fn = 0; fn < 2; ++fn) {
                int rr = wn * 32 + fn * 16 + (lane & 15);     // i in [0,64)
                bfr[fn] = *(bf16x8*)(smem + SC_QS + dc * 8192 +
                          (((uint32_t)(rr * 128 + kb)) ^ ((rr & 7) << 4)));
            }
#pragma unroll
            for (int fm = 0; fm < 2; ++fm)
#pragma unroll
                for (int fn = 0; fn < 2; ++fn)
                    acc[fm][fn] = __builtin_amdgcn_mfma_f32_16x16x32_bf16(
                        af[fm], bfr[fn], acc[fm][fn], 0, 0, 0);
        }
        // exp, Z partials, pack pairs, store to swizzled tile
#pragma unroll
        for (int fm = 0; fm < 2; ++fm)
#pragma unroll
            for (int fn = 0; fn < 2; ++fn) {
                float e0 = __expf(acc[fm][fn][0] * 0.0078125f);
                float e1 = __expf(acc[fm][fn][1] * 0.0078125f);
                float e2 = __expf(acc[fm][fn][2] * 0.0078125f);
                float e3 = __expf(acc[fm][fn][3] * 0.0078125f);
                zp[fn] += (e0 + e1) + (e2 + e3);
                uint2 pk;
                pk.x = bf16rtn(e0) | (bf16rtn(e1) << 16);
                pk.y = bf16rtn(e2) | (bf16rtn(e3) << 16);
                int j = sc * 128 + wm * 32 + fm * 16 + (lane >> 4) * 4;
                int i = wn * 32 + fn * 16 + (lane & 15);
                int kc = j >> 6, kk = j & 63;
                uint32_t byte = ((uint32_t)(i * 128 + kk * 2)) ^ ((uint32_t)((i & 7) << 4));
                *(uint2*)(Ewsw + (((size_t)((h * 8 + it) * 8 + kc)) << 13) + byte) = pk;
            }
    }
    zp[0] += __shfl_xor(zp[0], 16); zp[0] += __shfl_xor(zp[0], 32);
    zp[1] += __shfl_xor(zp[1], 16); zp[1] += __shfl_xor(zp[1], 32);
    if (lane < 16) {
        atomicAdd((float*)(smem + SC_ZS) + wn * 32 + lane,      zp[0]);
        atomicAdd((float*)(smem + SC_ZS) + wn * 32 + 16 + lane, zp[1]);
    }
    __syncthreads();
    if (t < 64) Zg[(size_t)h * NL + it * 64 + t] = *((float*)(smem + SC_ZS) + t);
}

// ---------------------------------------------------------------------------
// Energy GEMM (R7 math; T4 counted-vmcnt 2-barrier K-loop).  Block =
// (g=(h,it of 128 rows), nb of 192 cols), n = b*21+c (N=1344 exact).
// Per kc: issue stage(kc+1) -> s_waitcnt vmcnt(2) (stage kc landed; the 2
// just-issued loads stay in flight) -> s_barrier -> compute -> s_barrier.
// All in-loop ds_reads are consumed by MFMA before the barrier, so no lgkm
// drain is needed; only the 2 gl16s to the OTHER buffer span the barriers.
#define GE_AB   0        // 2 x 16384 A dbuf
#define GE_RACC 0        // 32*193*4 = 24704 (epilogue, reuses AB)
#define GE_XS   32768    // 10*130 u32 = 5200 -> 5248
#define GE_VS   38016    // 441 f32 = 1764
#define GE_TOT  39808

__global__ __launch_bounds__(512, 4)
void gemm_energy(const uint8_t* __restrict__ Ew, const int* __restrict__ x,
                 const float* __restrict__ Zg, const float* __restrict__ V,
                 float* __restrict__ out) {
    extern __shared__ uint8_t smem[];
    uint32_t* xs = (uint32_t*)(smem + GE_XS);
    float*    Vs = (float*)(smem + GE_VS);
    float*    Racc = (float*)(smem + GE_RACC);

    // XCD swizzle: 7 nb-replicas of a (h,it) panel share bid mod 8.
    int bid = blockIdx.x;
    int xcd = bid & 7, q = bid >> 3;
    int nb = q % 7, g = (q / 7) * 8 + xcd;   // g in [0,128)
    int h = g >> 2, it = g & 3;
    int n0 = nb * 192;
    int bstart = n0 / 21;
    int bend = (n0 + 191) / 21;
    int bcnt = bend - bstart + 1;            // 9 or 10

    int t = threadIdx.x, lane = t & 63, wv = t >> 6;
    int wm = wv >> 2, wn = wv & 3;           // 2(M) x 4(N)

    // ---- prologue staging: A chunk 0 (gl16), xs, Vs
    const uint8_t* A0 = Ew + (((size_t)(h * 8 + it * 2) * 8) << 13);
    const uint8_t* A1 = Ew + (((size_t)(h * 8 + it * 2 + 1) * 8) << 13);
#define GE_STAGE(p, kc) do { \
        gl16(A0 + (((size_t)(kc)) << 13) + t * 16, smem + GE_AB + (p) * 16384 + t * 16); \
        gl16(A1 + (((size_t)(kc)) << 13) + t * 16, smem + GE_AB + (p) * 16384 + 8192 + t * 16); \
    } while (0)
    GE_STAGE(0, 0);

    for (int idx = t; idx < bcnt * 128; idx += 512) {
        int s = idx >> 7, w = idx & 127;
        int4 xv = *(const int4*)(x + (size_t)(bstart + s) * NL + w * 4);
        xs[s * 130 + w] = (uint32_t)(xv.x & 0xff) | ((uint32_t)(xv.y & 0xff) << 8)
                        | ((uint32_t)(xv.z & 0xff) << 16) | ((uint32_t)(xv.w & 0xff) << 24);
    }
    for (int idx = t; idx < NAA * NAA; idx += 512) Vs[idx] = V[h * (NAA * NAA) + idx];

    int ccol[3], slotc[3];
#pragma unroll
    for (int fn = 0; fn < 3; ++fn) {
        int n = n0 + wn * 48 + fn * 16 + (lane & 15);
        int b = n / 21;
        ccol[fn] = n - b * 21;
        slotc[fn] = b - bstart;
    }

    f32x4 acc[4][3];
#pragma unroll
    for (int fm = 0; fm < 4; ++fm)
#pragma unroll
        for (int fn = 0; fn < 3; ++fn) acc[fm][fn] = (f32x4){0.f,0.f,0.f,0.f};

    __syncthreads();   // full drain once: stage(0), xs, Vs ready

    for (int kc = 0; kc < 8; ++kc) {
        int p = kc & 1;
        if (kc < 7) {
            GE_STAGE(p ^ 1, kc + 1);   // 2 gl16s stay in flight across barriers
            asm volatile("s_waitcnt vmcnt(2)" ::: "memory");   // stage(kc) landed
        } else {
            asm volatile("s_waitcnt vmcnt(0)" ::: "memory");
        }
        __builtin_amdgcn_s_barrier();           // all waves: buf p fully staged
        __builtin_amdgcn_sched_barrier(0);

#pragma unroll
        for (int ks = 0; ks < 2; ++ks) {
            int kb = (ks * 32 + (lane >> 4) * 8) * 2;
            bf16x8 af[4];
#pragma unroll
            for (int fm = 0; fm < 4; ++fm) {
                int r6 = fm * 16 + (lane & 15);
                af[fm] = *(bf16x8*)(smem + GE_AB + p * 16384 + wm * 8192 +
                          (((uint32_t)(r6 * 128 + kb)) ^ ((r6 & 7) << 4)));
            }
            int k0w = kc * 16 + ks * 8 + (lane >> 4) * 2;
            bf16x8 bfr[3];
#pragma unroll
            for (int fn = 0; fn < 3; ++fn) {
                uint2 ww = *(const uint2*)(xs + slotc[fn] * 130 + k0w);
                uint32_t c = (uint32_t)ccol[fn];
                union { uint32_t u[4]; bf16x8 v; } pk;
#pragma unroll
                for (int pq = 0; pq < 4; ++pq) {
                    uint32_t w = (pq < 2) ? ww.x : ww.y;
                    uint32_t sh = (pq & 1) * 16;
                    uint32_t b0 = (w >> sh) & 0xffu, b1 = (w >> (sh + 8)) & 0xffu;
                    pk.u[pq] = ((b0 == c) ? 0x3F80u : 0u) | ((b1 == c) ? 0x3F800000u : 0u);
                }
                bfr[fn] = pk.v;
            }
#pragma unroll
            for (int fm = 0; fm < 4; ++fm)
#pragma unroll
                for (int fn = 0; fn < 3; ++fn)
                    acc[fm][fn] = __builtin_amdgcn_mfma_f32_16x16x32_bf16(
                        af[fm], bfr[fn], acc[fm][fn], 0, 0, 0);
        }
        __builtin_amdgcn_sched_barrier(0);
        __builtin_amdgcn_s_barrier();           // all waves done reading buf p
        __builtin_amdgcn_sched_barrier(0);
    }
    __syncthreads();   // before Racc overwrites tile space (drains leftovers)

    // ---- epilogue: four 32-row windows through Racc (stride 193, 24.7KB)
    float vsum = 0.f;
    int srow = lane & 31;
    int s = wv * 2 + (lane >> 5);            // batch slot 0..15
#pragma unroll
    for (int w = 0; w < 4; ++w) {
        if (wm == (w >> 1)) {
#pragma unroll
            for (int f = 0; f < 2; ++f) {
                int fm = (w & 1) * 2 + f;
#pragma unroll
                for (int fn = 0; fn < 3; ++fn) {
                    int col = wn * 48 + fn * 16 + (lane & 15);
                    int rb = f * 16 + (lane >> 4) * 4;
#pragma unroll
                    for (int r = 0; r < 4; ++r)
                        Racc[(rb + r) * 193 + col] = acc[fm][fn][r];
                }
            }
        }
        __syncthreads();
        int ig = it * 128 + w * 32 + srow;
        float rz = 1.0f / Zg[(size_t)h * NL + ig];
        if (s < bcnt) {
            int b = bstart + s;
            uint32_t xw = xs[s * 130 + (ig >> 2)];
            int a = (int)((xw >> ((ig & 3) * 8)) & 0xffu);
            int off = b * 21 - n0;
            int clo = off < 0 ? -off : 0;
            int chi = (192 - off) < 21 ? (192 - off) : 21;
            float dot = 0.f;
            for (int c = clo; c < chi; ++c)
                dot += Vs[a * NAA + c] * Racc[srow * 193 + off + c];
            vsum += dot * rz;
        }
        __syncthreads();
    }
    // reduce the 32 rows within each half-wave, one atomic per (wave, half)
#pragma unroll
    for (int o = 1; o < 32; o <<= 1) vsum += __shfl_xor(vsum, o);
    if (srow == 0 && s < bcnt) atomicAdd(&out[bstart + s], -vsum);
}

// ---------------------------------------------------------------------------
extern "C" void kernel_launch(void* const* d_in, const int* in_sizes, int n_in,
                              void* d_out, int out_size, void* d_ws, size_t ws_size,
                              hipStream_t stream) {
    const int*   x = (const int*)d_in[0];
    const float* Q = (const float*)d_in[1];
    const float* K = (const float*)d_in[2];
    const float* V = (const float*)d_in[3];
    float* out = (float*)d_out;
    uint8_t* ws = (uint8_t*)d_ws;

    uint8_t*  Ewsw = ws + EW_OFF;
    uint32_t* Qb   = (uint32_t*)(ws + QB_OFF);
    uint32_t* Kb   = (uint32_t*)(ws + KB_OFF);
    float*    Zg   = (float*)(ws + ZG_OFF);

    hipMemsetAsync(d_out, 0, NB * sizeof(float), stream);
    prep_qk<<<8192, 256, 0, stream>>>(Q, K, Qb, Kb);
    (void)hipFuncSetAttribute((const void*)scores_mfma,
                              hipFuncAttributeMaxDynamicSharedMemorySize, SC_TOT);
    scores_mfma<<<256, 512, SC_TOT, stream>>>((const uint8_t*)Qb, (const uint8_t*)Kb,
                                              Ewsw, Zg);
    (void)hipFuncSetAttribute((const void*)gemm_energy,
                              hipFuncAttributeMaxDynamicSharedMemorySize, GE_TOT);
    gemm_energy<<<896, 512, GE_TOT, stream>>>((const uint8_t*)Ewsw, x, Zg, V, out);
}

// Round 9
// 78.734 us; speedup vs baseline: 1.0397x; 1.0397x over previous
//
#include <hip/hip_runtime.h>
#include <hip/hip_bf16.h>
#include <stdint.h>

// Problem constants (B=64, L=512, H=32, D=128, 21 amino acids)
#define NH  32
#define NL  512
#define ND  128
#define NB  64
#define NAA 21

// ws layout:
//   Ewsw: bf16 exp(scores) UNNORMALIZED, swizzled 8KB tiles [h][it64][kc]  16 MB @ 0
//   Qb/Kb: bf16 swizzled 8KB tiles [h][pt 0..7][dc 0..1] (64 pos x 64 d)   2 MB each
//   Zg  : f32 row sums [h][i]                                              64 KB
//   Bf  : one-hot B in MFMA-fragment order                               1.4 MB @ 21MB
//         frag id f = ((nb*8+kc)*2+ks)*12 + (3*wn+fn); 16B per lane
#define EW_OFF 0
#define QB_OFF (16u << 20)
#define KB_OFF (18u << 20)
#define ZG_OFF (20u << 20)
#define BF_OFF (21u << 20)

typedef short bf16x8 __attribute__((ext_vector_type(8)));
typedef float f32x4  __attribute__((ext_vector_type(4)));

static __device__ __forceinline__ uint32_t bf16rtn(float f) {
    uint32_t u = __float_as_uint(f);
    return (u + 0x7fffu + ((u >> 16) & 1u)) >> 16;
}
static __device__ __forceinline__ void gl16(const void* g, void* l) {
    __builtin_amdgcn_global_load_lds(
        (const __attribute__((address_space(1))) uint32_t*)g,
        (__attribute__((address_space(3))) uint32_t*)l, 16, 0, 0);
}
// swizzled byte within a 64x64 bf16 tile: (r*128 + kk*2) ^ ((r&7)<<4)

// ---------------------------------------------------------------------------
// Q,K f32 -> bf16 swizzled tiles.  2^21 threads: bit20 selects Q/K.
__global__ void prep_qk(const float* __restrict__ Q, const float* __restrict__ K,
                        uint32_t* __restrict__ Qb, uint32_t* __restrict__ Kb) {
    uint32_t tid = blockIdx.x * 256 + threadIdx.x;
    const float* src = (tid >> 20) ? K : Q;
    uint32_t*    dst = (tid >> 20) ? Kb : Qb;
    uint32_t p = tid & 0xFFFFFu;
    uint32_t kk2 = p & 31, r = (p >> 5) & 63, dc = (p >> 11) & 1;
    uint32_t pt = (p >> 12) & 7, h = p >> 15;
    uint32_t pos = pt * 64 + r, d0 = dc * 64 + kk2 * 2;
    float2 v = *(const float2*)(src + ((size_t)(h * NL + pos) * ND + d0));
    uint32_t val = bf16rtn(v.x) | (bf16rtn(v.y) << 16);
    uint32_t byte = (r * 128 + kk2 * 4) ^ ((r & 7) << 4);
    dst[((((h * 8 + pt) * 2 + dc)) << 11) + (byte >> 2)] = val;
}

// ---------------------------------------------------------------------------
// One-hot B fragments, exactly the register image gemm's MFMA consumes.
// Thread = (f, lane): f = ((nb*8+kc)*2+ks)*12 + cg.  col = nb*192+cg*16+
// (lane&15), element e -> k = kc*64+ks*32+(lane>>4)*8+e.  86016 threads.
__global__ void prep_bfrag(const int* __restrict__ x, uint8_t* __restrict__ Bf) {
    int tid = blockIdx.x * 256 + threadIdx.x;
    int lane = tid & 63;
    int f  = tid >> 6;          // 0..1343
    int cg = f % 12;
    int t2 = f / 12;
    int ks = t2 & 1;
    int t3 = t2 >> 1;
    int kc = t3 & 7;
    int nb = t3 >> 3;
    int col = nb * 192 + cg * 16 + (lane & 15);
    int b = col / 21, c = col - b * 21;
    int k0 = kc * 64 + ks * 32 + (lane >> 4) * 8;
    const int* xp = x + (size_t)b * NL + k0;
    int4 x0 = *(const int4*)(xp);
    int4 x1 = *(const int4*)(xp + 4);
    uint4 pk;
    pk.x = ((x0.x == c) ? 0x3F80u : 0u) | ((x0.y == c) ? 0x3F800000u : 0u);
    pk.y = ((x0.z == c) ? 0x3F80u : 0u) | ((x0.w == c) ? 0x3F800000u : 0u);
    pk.z = ((x1.x == c) ? 0x3F80u : 0u) | ((x1.y == c) ? 0x3F800000u : 0u);
    pk.w = ((x1.z == c) ? 0x3F80u : 0u) | ((x1.w == c) ? 0x3F800000u : 0u);
    *(uint4*)(Bf + (size_t)tid * 16) = pk;
}

// ---------------------------------------------------------------------------
// scores via MFMA, SWAPPED operands: S^T = K(j rows) x Q(i cols) over d=128.
#define SC_QS 0        // 16KB: Q tiles dc=0,1
#define SC_KS 16384    // 32KB: K subchunk tiles q = jt*2+dc
#define SC_ZS 49152    // 64 f32
#define SC_TOT 49408

__global__ __launch_bounds__(512)
void scores_mfma(const uint8_t* __restrict__ Qb, const uint8_t* __restrict__ Kb,
                 uint8_t* __restrict__ Ewsw, float* __restrict__ Zg) {
    extern __shared__ uint8_t smem[];
    int h = blockIdx.x >> 3, it = blockIdx.x & 7;
    int t = threadIdx.x, lane = t & 63, wv = t >> 6;
    int wm = wv >> 1, wn = wv & 1;   // 4(Mj) x 2(Ni)

    const uint8_t* qsrc = Qb + (((size_t)(h * 8 + it) * 2) << 13);
    gl16(qsrc + t * 16,        smem + SC_QS + t * 16);
    gl16(qsrc + 8192 + t * 16, smem + SC_QS + 8192 + t * 16);
    if (t < 64) *(float*)(smem + SC_ZS + t * 4) = 0.f;

    float zp[2] = {0.f, 0.f};
    for (int sc = 0; sc < 4; ++sc) {
        __syncthreads();   // prev compute done reading Ks (and 1st: covers Q/Zs)
        const uint8_t* ksrc = Kb + (((size_t)(h * 8 + sc * 2) * 2) << 13);
#pragma unroll
        for (int q = 0; q < 4; ++q)
            gl16(ksrc + q * 8192 + t * 16, smem + SC_KS + q * 8192 + t * 16);
        __syncthreads();   // implicit vmcnt(0): K staged

        f32x4 acc[2][2];
#pragma unroll
        for (int fm = 0; fm < 2; ++fm)
#pragma unroll
            for (int fn = 0; fn < 2; ++fn) acc[fm][fn] = (f32x4){0.f,0.f,0.f,0.f};

#pragma unroll
        for (int ks = 0; ks < 4; ++ks) {
            int kb = ((ks & 1) * 32 + (lane >> 4) * 8) * 2;
            int dc = ks >> 1;
            bf16x8 af[2], bfr[2];
#pragma unroll
            for (int fm = 0; fm < 2; ++fm) {
                int rr = wm * 32 + fm * 16 + (lane & 15);     // j in [0,128)
                int rt = rr >> 6, r6 = rr & 63;
                af[fm] = *(bf16x8*)(smem + SC_KS + (rt * 2 + dc) * 8192 +
                          (((uint32_t)(r6 * 128 + kb)) ^ ((r6 & 7) << 4)));
            }
#pragma unroll
            for (int fn = 0; fn < 2; ++fn) {
                int rr = wn * 32 + fn * 16 + (lane & 15);     // i in [0,64)
                bfr[fn] = *(bf16x8*)(smem + SC_QS + dc * 8192 +
                          (((uint32_t)(rr * 128 + kb)) ^ ((rr & 7) << 4)));
            }
#pragma unroll
            for (int fm = 0; fm < 2; ++fm)
#pragma unroll
                for (int fn = 0; fn < 2; ++fn)
                    acc[fm][fn] = __builtin_amdgcn_mfma_f32_16x16x32_bf16(
                        af[fm], bfr[fn], acc[fm][fn], 0, 0, 0);
        }
        // exp, Z partials, pack pairs, store to swizzled tile
#pragma unroll
        for (int fm = 0; fm < 2; ++fm)
#pragma unroll
            for (int fn = 0; fn < 2; ++fn) {
                float e0 = __expf(acc[fm][fn][0] * 0.0078125f);
                float e1 = __expf(acc[fm][fn][1] * 0.0078125f);
                float e2 = __expf(acc[fm][fn][2] * 0.0078125f);
                float e3 = __expf(acc[fm][fn][3] * 0.0078125f);
                zp[fn] += (e0 + e1) + (e2 + e3);
                uint2 pk;
                pk.x = bf16rtn(e0) | (bf16rtn(e1) << 16);
                pk.y = bf16rtn(e2) | (bf16rtn(e3) << 16);
                int j = sc * 128 + wm * 32 + fm * 16 + (lane >> 4) * 4;
                int i = wn * 32 + fn * 16 + (lane & 15);
                int kc = j >> 6, kk = j & 63;
                uint32_t byte = ((uint32_t)(i * 128 + kk * 2)) ^ ((uint32_t)((i & 7) << 4));
                *(uint2*)(Ewsw + (((size_t)((h * 8 + it) * 8 + kc)) << 13) + byte) = pk;
            }
    }
    zp[0] += __shfl_xor(zp[0], 16); zp[0] += __shfl_xor(zp[0], 32);
    zp[1] += __shfl_xor(zp[1], 16); zp[1] += __shfl_xor(zp[1], 32);
    if (lane < 16) {
        atomicAdd((float*)(smem + SC_ZS) + wn * 32 + lane,      zp[0]);
        atomicAdd((float*)(smem + SC_ZS) + wn * 32 + 16 + lane, zp[1]);
    }
    __syncthreads();
    if (t < 64) Zg[(size_t)h * NL + it * 64 + t] = *((float*)(smem + SC_ZS) + t);
}

// ---------------------------------------------------------------------------
// Energy GEMM (R7 sync structure; B from precomputed global fragments).
// Block = (g=(h,it of 128 rows), nb of 192 cols), n = b*21+c (N=1344 exact).
// A: gl16 double-buffer, stage kc+1 at top, one __syncthreads per kc.
// B: 6 coalesced dwordx4 register loads per kc (no VALU, no LDS).
#define GE_AB   0        // 2 x 16384 A dbuf
#define GE_RACC 0        // 32*193*4 = 24704 (epilogue, reuses AB)
#define GE_XS   32768    // 10*129 u32 = 5160 -> 5248
#define GE_VS   38016    // 441 f32 = 1764
#define GE_TOT  39808

__global__ __launch_bounds__(512, 4)
void gemm_energy(const uint8_t* __restrict__ Ew, const uint8_t* __restrict__ Bf,
                 const int* __restrict__ x, const float* __restrict__ Zg,
                 const float* __restrict__ V, float* __restrict__ out) {
    extern __shared__ uint8_t smem[];
    uint32_t* xs = (uint32_t*)(smem + GE_XS);
    float*    Vs = (float*)(smem + GE_VS);
    float*    Racc = (float*)(smem + GE_RACC);

    // XCD swizzle: 7 nb-replicas of a (h,it) panel share bid mod 8.
    int bid = blockIdx.x;
    int xcd = bid & 7, q = bid >> 3;
    int nb = q % 7, g = (q / 7) * 8 + xcd;   // g in [0,128)
    int h = g >> 2, it = g & 3;
    int n0 = nb * 192;
    int bstart = n0 / 21;
    int bend = (n0 + 191) / 21;
    int bcnt = bend - bstart + 1;            // 9 or 10

    int t = threadIdx.x, lane = t & 63, wv = t >> 6;
    int wm = wv >> 2, wn = wv & 3;           // 2(M) x 4(N)

    // ---- prologue staging: A chunk 0 (gl16), xs, Vs
    const uint8_t* A0 = Ew + (((size_t)(h * 8 + it * 2) * 8) << 13);
    const uint8_t* A1 = Ew + (((size_t)(h * 8 + it * 2 + 1) * 8) << 13);
#define GE_STAGE(p, kc) do { \
        gl16(A0 + (((size_t)(kc)) << 13) + t * 16, smem + GE_AB + (p) * 16384 + t * 16); \
        gl16(A1 + (((size_t)(kc)) << 13) + t * 16, smem + GE_AB + (p) * 16384 + 8192 + t * 16); \
    } while (0)
    GE_STAGE(0, 0);

    for (int idx = t; idx < bcnt * 128; idx += 512) {
        int s = idx >> 7, w = idx & 127;
        int4 xv = *(const int4*)(x + (size_t)(bstart + s) * NL + w * 4);
        xs[s * 129 + w] = (uint32_t)(xv.x & 0xff) | ((uint32_t)(xv.y & 0xff) << 8)
                        | ((uint32_t)(xv.z & 0xff) << 16) | ((uint32_t)(xv.w & 0xff) << 24);
    }
    for (int idx = t; idx < NAA * NAA; idx += 512) Vs[idx] = V[h * (NAA * NAA) + idx];

    // B fragment base for this wave: frag id = ((nb*8+kc)*2+ks)*12 + 3*wn+fn
    const uint8_t* bfw = Bf + ((size_t)(nb * 192 + 3 * wn)) * 1024 + lane * 16;

    // hoisted swizzled A-fragment offsets (per-lane constants)
    uint32_t aoff[2][4];
#pragma unroll
    for (int ks = 0; ks < 2; ++ks)
#pragma unroll
        for (int fm = 0; fm < 4; ++fm) {
            int r6 = fm * 16 + (lane & 15);
            int kb = (ks * 32 + (lane >> 4) * 8) * 2;
            aoff[ks][fm] = (uint32_t)(wm * 8192 +
                           (((uint32_t)(r6 * 128 + kb)) ^ ((r6 & 7) << 4)));
        }

    f32x4 acc[4][3];
#pragma unroll
    for (int fm = 0; fm < 4; ++fm)
#pragma unroll
        for (int fn = 0; fn < 3; ++fn) acc[fm][fn] = (f32x4){0.f,0.f,0.f,0.f};

    __syncthreads();   // full drain: stage(0), xs, Vs ready

    for (int kc = 0; kc < 8; ++kc) {
        int p = kc & 1;
        if (kc < 7) GE_STAGE(p ^ 1, kc + 1);   // overlaps with compute below
        // B fragments for this kc: 6 coalesced 16B register loads
        bf16x8 bfr[2][3];
#pragma unroll
        for (int ks = 0; ks < 2; ++ks)
#pragma unroll
            for (int fn = 0; fn < 3; ++fn)
                bfr[ks][fn] = *(const bf16x8*)(bfw + kc * 24576 + ks * 12288 + fn * 1024);
#pragma unroll
        for (int ks = 0; ks < 2; ++ks) {
            bf16x8 af[4];
#pragma unroll
            for (int fm = 0; fm < 4; ++fm)
                af[fm] = *(bf16x8*)(smem + GE_AB + p * 16384 + aoff[ks][fm]);
#pragma unroll
            for (int fm = 0; fm < 4; ++fm)
#pragma unroll
                for (int fn = 0; fn < 3; ++fn)
                    acc[fm][fn] = __builtin_amdgcn_mfma_f32_16x16x32_bf16(
                        af[fm], bfr[ks][fn], acc[fm][fn], 0, 0, 0);
        }
        __syncthreads();   // drains stage(kc+1) gl16s; orders dbuf reuse
    }

    // ---- epilogue: four 32-row windows through Racc (stride 193, 24.7KB)
    float vsum = 0.f;
    int srow = lane & 31;
    int s = wv * 2 + (lane >> 5);            // batch slot 0..15
#pragma unroll
    for (int w = 0; w < 4; ++w) {
        if (wm == (w >> 1)) {
#pragma unroll
            for (int f = 0; f < 2; ++f) {
                int fm = (w & 1) * 2 + f;
#pragma unroll
                for (int fn = 0; fn < 3; ++fn) {
                    int col = wn * 48 + fn * 16 + (lane & 15);
                    int rb = f * 16 + (lane >> 4) * 4;
#pragma unroll
                    for (int r = 0; r < 4; ++r)
                        Racc[(rb + r) * 193 + col] = acc[fm][fn][r];
                }
            }
        }
        __syncthreads();
        int ig = it * 128 + w * 32 + srow;
        float rz = 1.0f / Zg[(size_t)h * NL + ig];
        if (s < bcnt) {
            int b = bstart + s;
            uint32_t xw = xs[s * 129 + (ig >> 2)];
            int a = (int)((xw >> ((ig & 3) * 8)) & 0xffu);
            int off = b * 21 - n0;
            int clo = off < 0 ? -off : 0;
            int chi = (192 - off) < 21 ? (192 - off) : 21;
            float dot = 0.f;
            for (int c = clo; c < chi; ++c)
                dot += Vs[a * NAA + c] * Racc[srow * 193 + off + c];
            vsum += dot * rz;
        }
        __syncthreads();
    }
    // reduce the 32 rows within each half-wave, one atomic per (wave, half)
#pragma unroll
    for (int o = 1; o < 32; o <<= 1) vsum += __shfl_xor(vsum, o);
    if (srow == 0 && s < bcnt) atomicAdd(&out[bstart + s], -vsum);
}

// ---------------------------------------------------------------------------
extern "C" void kernel_launch(void* const* d_in, const int* in_sizes, int n_in,
                              void* d_out, int out_size, void* d_ws, size_t ws_size,
                              hipStream_t stream) {
    const int*   x = (const int*)d_in[0];
    const float* Q = (const float*)d_in[1];
    const float* K = (const float*)d_in[2];
    const float* V = (const float*)d_in[3];
    float* out = (float*)d_out;
    uint8_t* ws = (uint8_t*)d_ws;

    uint8_t*  Ewsw = ws + EW_OFF;
    uint32_t* Qb   = (uint32_t*)(ws + QB_OFF);
    uint32_t* Kb   = (uint32_t*)(ws + KB_OFF);
    float*    Zg   = (float*)(ws + ZG_OFF);
    uint8_t*  Bfr  = ws + BF_OFF;

    hipMemsetAsync(d_out, 0, NB * sizeof(float), stream);
    prep_qk<<<8192, 256, 0, stream>>>(Q, K, Qb, Kb);
    prep_bfrag<<<336, 256, 0, stream>>>(x, Bfr);
    (void)hipFuncSetAttribute((const void*)scores_mfma,
                              hipFuncAttributeMaxDynamicSharedMemorySize, SC_TOT);
    scores_mfma<<<256, 512, SC_TOT, stream>>>((const uint8_t*)Qb, (const uint8_t*)Kb,
                                              Ewsw, Zg);
    (void)hipFuncSetAttribute((const void*)gemm_energy,
                              hipFuncAttributeMaxDynamicSharedMemorySize, GE_TOT);
    gemm_energy<<<896, 512, GE_TOT, stream>>>((const uint8_t*)Ewsw, Bfr, x, Zg, V, out);
}